// Round 10
// baseline (196.854 us; speedup 1.0000x reference)
//
#include <hip/hip_runtime.h>
#include <math.h>

// ---------------- problem constants (from reference) ----------------
#define N_NODES 50000
#define N_PAD   50048                 // padded to 128-row tiles (391 tiles)
#define N_EDGES 800000
#define ETOT    (N_EDGES + N_NODES)   // self-loops appended
#define NFEAT   128
#define NHID    16
#define HEADS   8
#define HD      (HEADS * NHID)        // 128
#define NCLASS  2
#define NEG     0.2f
#define NBLK_SCAN 49                  // ceil(50000/1024)
#define WROWS   144                   // 128 W1t rows + 16 V^T rows
#define NB_GEMM (N_PAD / 128)         // 391
#define NB_BUILD ((ETOT + 255) / 256) // 3321

typedef short  bf16x8 __attribute__((ext_vector_type(8)));
typedef float  f32x4  __attribute__((ext_vector_type(4)));
typedef unsigned short ushort;
typedef ushort u16x4 __attribute__((ext_vector_type(4)));
typedef unsigned long long ull;

__device__ __forceinline__ ushort f2bf(float f) {   // RNE f32->bf16
    unsigned u = __float_as_uint(f);
    unsigned r = (u + 0x7fffu + ((u >> 16) & 1u)) >> 16;
    return (ushort)r;
}
__device__ __forceinline__ float bf2f(ushort u) {
    return __uint_as_float(((unsigned)u) << 16);
}

// =====================================================================
// K0 (fused): blocks 0..NB_GEMM-1 run the MFMA GEMM
//   [h1 | attention dots] = x_bf16 @ [W1 | V]; W1t+V^T built per-block
//   in LDS from f32 W1/as1/ad1 (L2-hot). A-fragments read directly from
//   global x (each element exactly once per wave).
// Blocks NB_GEMM..: edge pass — per-block i64/i32 detection, degree
//   histogram (deg pre-zeroed by hipMemsetAsync), epack
//   (s | d<<16 | rank<<32) for the later atomic-free scatter.
// =====================================================================
__global__ __launch_bounds__(256) void k_fused(
        const void* __restrict__ ei, const float* __restrict__ x,
        const float* __restrict__ W1, const float* __restrict__ as1,
        const float* __restrict__ ad1,
        int* __restrict__ deg, ull* __restrict__ epack,
        ushort* __restrict__ h1b, float* __restrict__ asrc1,
        float* __restrict__ adst1) {
    __shared__ char Wl[WROWS * 256];   // 36 KB (swizzled)
    __shared__ int s_any;
    const int tid = threadIdx.x;

    if (blockIdx.x >= NB_GEMM) {
        // ----------------- build role -----------------
        const int e = (blockIdx.x - NB_GEMM) * 256 + tid;
        if (tid == 0) s_any = 0;
        __syncthreads();
        if (e < N_EDGES) {
            if (((const unsigned*)ei)[2 * e + 1] != 0u) s_any = 1;
        }
        __syncthreads();
        if (e >= ETOT) return;
        const bool i64 = (s_any == 0);
        int s, d;
        if (e < N_EDGES) {
            if (i64) {
                const long long* p = (const long long*)ei;
                s = (int)p[e];
                d = (int)p[N_EDGES + e];
            } else {
                const int* p = (const int*)ei;
                s = p[e];
                d = p[N_EDGES + e];
            }
        } else {
            s = e - N_EDGES;
            d = s;
        }
        unsigned rank = (unsigned)atomicAdd(&deg[d], 1);
        epack[e] = (ull)(unsigned)(s | (d << 16)) | ((ull)rank << 32);
        return;
    }

    // ----------------- gemm role -----------------
    const int l = tid & 63, w = tid >> 6;
    // stage Wl rows 0..127: transpose W1 (f32 [k][c]) -> bf16 [c][k]
    // 128 rows x 32 chunks (4 k-values, 8 B) = 4096 chunks, 16/thread
    #pragma unroll
    for (int it = 0; it < 16; ++it) {
        int q = it * 256 + tid;
        int row = q >> 5, kc = q & 31, k0 = kc * 4;
        u16x4 o;
        #pragma unroll
        for (int j = 0; j < 4; j++) o[j] = f2bf(W1[(k0 + j) * HD + row]);
        int a = (row * 256 + kc * 8) ^ ((row & 7) << 4);
        *(u16x4*)(Wl + a) = o;
    }
    // stage Wl rows 128..143: V^T[j][k] = sum_t W1[k][head*16+t]*av[...]
    // 16 rows x 32 chunks = 512 chunks, 2/thread
    #pragma unroll
    for (int it = 0; it < 2; ++it) {
        int q = it * 256 + tid;
        int j = q >> 5, kc = q & 31, k0 = kc * 4;
        int row = 128 + j, head = j & 7;
        const float* av = (j < 8) ? as1 : ad1;
        u16x4 o;
        #pragma unroll
        for (int jj = 0; jj < 4; jj++) {
            float sdot = 0.f;
            #pragma unroll
            for (int t = 0; t < 16; t++)
                sdot = fmaf(W1[(k0 + jj) * HD + head * 16 + t], av[head * 16 + t], sdot);
            o[jj] = f2bf(sdot);
        }
        int a = (row * 256 + kc * 8) ^ ((row & 7) << 4);
        *(u16x4*)(Wl + a) = o;
    }
    __syncthreads();
    const int tile0 = blockIdx.x * 128;
    f32x4 acc[2][9];
    #pragma unroll
    for (int r = 0; r < 2; r++)
        #pragma unroll
        for (int i = 0; i < 9; i++) acc[r][i] = (f32x4){0.f, 0.f, 0.f, 0.f};
    #pragma unroll
    for (int kk = 0; kk < 4; ++kk) {                 // K step = 32 bf16
        bf16x8 af[2];
        #pragma unroll
        for (int r = 0; r < 2; ++r) {
            const int grow = tile0 + (w + 4 * r) * 16 + (l & 15);
            const int koff = kk * 32 + (l >> 4) * 8;
            float4 xa = make_float4(0.f, 0.f, 0.f, 0.f);
            float4 xb = make_float4(0.f, 0.f, 0.f, 0.f);
            if (grow < N_NODES) {
                xa = *(const float4*)(x + (size_t)grow * NFEAT + koff);
                xb = *(const float4*)(x + (size_t)grow * NFEAT + koff + 4);
            }
            bf16x8 t;
            t[0] = (short)f2bf(xa.x); t[1] = (short)f2bf(xa.y);
            t[2] = (short)f2bf(xa.z); t[3] = (short)f2bf(xa.w);
            t[4] = (short)f2bf(xb.x); t[5] = (short)f2bf(xb.y);
            t[6] = (short)f2bf(xb.z); t[7] = (short)f2bf(xb.w);
            af[r] = t;
        }
        #pragma unroll
        for (int nb = 0; nb < 9; ++nb) {
            const int bcol = nb * 16 + (l & 15);
            const int bbyte = (bcol * 256 + kk * 64 + ((l >> 4) << 4)) ^ ((bcol & 7) << 4);
            bf16x8 bfm = *(const bf16x8*)(Wl + bbyte);
            acc[0][nb] = __builtin_amdgcn_mfma_f32_16x16x32_bf16(af[0], bfm, acc[0][nb], 0, 0, 0);
            acc[1][nb] = __builtin_amdgcn_mfma_f32_16x16x32_bf16(af[1], bfm, acc[1][nb], 0, 0, 0);
        }
    }
    // D layout: col = nb*16 + (l&15), row = (w+4r)*16 + (l>>4)*4 + i
    #pragma unroll
    for (int r = 0; r < 2; r++) {
        #pragma unroll
        for (int nb = 0; nb < 8; nb++) {
            #pragma unroll
            for (int i = 0; i < 4; i++) {
                const int row = tile0 + (w + 4 * r) * 16 + ((l >> 4) << 2) + i;
                h1b[(size_t)row * HD + nb * 16 + (l & 15)] = f2bf(acc[r][nb][i]);
            }
        }
        const int j = l & 15;
        #pragma unroll
        for (int i = 0; i < 4; i++) {
            const int row = tile0 + (w + 4 * r) * 16 + ((l >> 4) << 2) + i;
            if (row < N_NODES) {
                const float v = acc[r][8][i];
                if (j < 8) asrc1[row * HEADS + j]       = v;
                else       adst1[row * HEADS + (j - 8)] = v;
            }
        }
    }
}

// =====================================================================
// K1: per-1024-block exclusive scan of deg -> part, block totals -> bsum
// =====================================================================
__global__ __launch_bounds__(1024) void k_scan1(const int* __restrict__ deg,
                                                int* __restrict__ part,
                                                int* __restrict__ bsum) {
    __shared__ int wsum[16];
    const int tid = threadIdx.x, lane = tid & 63, wid = tid >> 6;
    int i = blockIdx.x * 1024 + tid;
    int v = (i < N_NODES) ? deg[i] : 0;
    int orig = v;
    #pragma unroll
    for (int off = 1; off < 64; off <<= 1) {
        int t = __shfl_up(v, off, 64);
        if (lane >= off) v += t;
    }
    if (lane == 63) wsum[wid] = v;
    __syncthreads();
    if (wid == 0 && lane < 16) {
        int w = wsum[lane];
        #pragma unroll
        for (int off = 1; off < 16; off <<= 1) {
            int t = __shfl_up(w, off, 16);
            if (lane >= off) w += t;
        }
        wsum[lane] = w;
    }
    __syncthreads();
    int ex = v - orig + (wid ? wsum[wid - 1] : 0);
    if (i < N_NODES) part[i] = ex;
    if (tid == 1023) bsum[blockIdx.x] = wsum[15];
}

// =====================================================================
// K2: fused top-scan + row_ptr write + atomic-free scatter.
// =====================================================================
__global__ void k_scatter3(const ull* __restrict__ epack, const int* __restrict__ part,
                           const int* __restrict__ bsum,
                           int* __restrict__ row_ptr, ushort* __restrict__ csr) {
    __shared__ int topx[64];
    if (threadIdx.x < 64) {
        int lane = threadIdx.x;
        int v = (lane < NBLK_SCAN) ? bsum[lane] : 0;
        int orig = v;
        #pragma unroll
        for (int off = 1; off < 64; off <<= 1) {
            int t = __shfl_up(v, off, 64);
            if (lane >= off) v += t;
        }
        topx[lane] = v - orig;     // exclusive prefix
    }
    __syncthreads();
    int i = blockIdx.x * 256 + threadIdx.x;
    if (i < N_NODES) row_ptr[i] = part[i] + topx[i >> 10];
    if (i == 0) row_ptr[N_NODES] = ETOT;
    if (i < ETOT) {
        ull v = epack[i];
        int s = (int)(v & 0xFFFF);
        int d = (int)((v >> 16) & 0xFFFF);
        int r = (int)(v >> 32);
        csr[part[d] + topx[d >> 10] + r] = (ushort)s;
    }
}

// =====================================================================
// K3: layer-1 aggregation, no max-subtraction (bounded logits),
//     2-DEEP software pipeline: H-vectors prefetched 1 batch ahead,
//     indices+logits 2 batches ahead; branch-free (min-clamped tails).
//     One wave per node; lane sl owns 4 channels; halves take disjoint
//     4-edge sub-batches. Epilogue: bias+ELU+W2(128->2)+att2 dots ->
//     nd[n] = {h2_0, h2_1, asrc2, adst2}.
// =====================================================================
__global__ __launch_bounds__(256) void k_agg1(
        const int* __restrict__ row_ptr, const ushort* __restrict__ csr,
        const float* __restrict__ asrc1, const float* __restrict__ adst1,
        const ushort* __restrict__ h1b, const float* __restrict__ bias1,
        const float* __restrict__ W2, const float* __restrict__ as2,
        const float* __restrict__ ad2, float4* __restrict__ nd) {
    const int n = blockIdx.x * 4 + (threadIdx.x >> 6);
    if (n >= N_NODES) return;
    const int lane = threadIdx.x & 63;
    const int half = lane >> 5, sl = lane & 31;
    const int h = sl >> 2;           // head of this lane's 4 channels
    const int c0 = sl * 4;
    const float adst = adst1[n * HEADS + h];
    const int beg = row_ptr[n];
    const int deg = row_ptr[n + 1] - beg;   // >= 1 (self-loop)
    const int nIter = (deg + 7) >> 3;
    float den = 0.f, a0 = 0.f, a1 = 0.f, a2 = 0.f, a3 = 0.f;

#define LDI(IT, S0, S1, S2, S3) { const int j0_ = (IT) * 8 + half * 4;        \
    S0 = csr[beg + min(j0_ + 0, deg - 1)]; S1 = csr[beg + min(j0_ + 1, deg - 1)]; \
    S2 = csr[beg + min(j0_ + 2, deg - 1)]; S3 = csr[beg + min(j0_ + 3, deg - 1)]; }
#define LDR(S0, S1, S2, S3, R0, R1, R2, R3) {                                 \
    R0 = asrc1[S0 * HEADS + h]; R1 = asrc1[S1 * HEADS + h];                   \
    R2 = asrc1[S2 * HEADS + h]; R3 = asrc1[S3 * HEADS + h]; }
#define LDH(S0, S1, S2, S3, H0, H1, H2, H3) {                                 \
    H0 = *(const u16x4*)(h1b + (size_t)S0 * HD + c0);                         \
    H1 = *(const u16x4*)(h1b + (size_t)S1 * HD + c0);                         \
    H2 = *(const u16x4*)(h1b + (size_t)S2 * HD + c0);                         \
    H3 = *(const u16x4*)(h1b + (size_t)S3 * HD + c0); }

    int   sA0, sA1, sA2, sA3, sB0, sB1, sB2, sB3;
    float rA0, rA1, rA2, rA3, rB0, rB1, rB2, rB3;
    u16x4 HA0, HA1, HA2, HA3;
    LDI(0, sA0, sA1, sA2, sA3);
    LDR(sA0, sA1, sA2, sA3, rA0, rA1, rA2, rA3);
    LDH(sA0, sA1, sA2, sA3, HA0, HA1, HA2, HA3);
    LDI(1, sB0, sB1, sB2, sB3);
    LDR(sB0, sB1, sB2, sB3, rB0, rB1, rB2, rB3);

    for (int it = 0; it < nIter; ++it) {
        // prefetch H for batch it+1 (from sB, already resident)
        u16x4 HB0, HB1, HB2, HB3;
        LDH(sB0, sB1, sB2, sB3, HB0, HB1, HB2, HB3);
        // prefetch indices + raw logits for batch it+2 (clamped)
        int   sC0, sC1, sC2, sC3;
        float rC0, rC1, rC2, rC3;
        LDI(it + 2, sC0, sC1, sC2, sC3);
        LDR(sC0, sC1, sC2, sC3, rC0, rC1, rC2, rC3);
        // compute batch it (registers only; H arrived during prior iter)
        const int j0 = it * 8 + half * 4;
        float e0 = rA0 + adst, e1 = rA1 + adst, e2 = rA2 + adst, e3 = rA3 + adst;
        e0 = (e0 > 0.f) ? e0 : NEG * e0;
        e1 = (e1 > 0.f) ? e1 : NEG * e1;
        e2 = (e2 > 0.f) ? e2 : NEG * e2;
        e3 = (e3 > 0.f) ? e3 : NEG * e3;
        const float w0 = (j0 + 0 < deg) ? __expf(e0) : 0.f;
        const float w1 = (j0 + 1 < deg) ? __expf(e1) : 0.f;
        const float w2 = (j0 + 2 < deg) ? __expf(e2) : 0.f;
        const float w3 = (j0 + 3 < deg) ? __expf(e3) : 0.f;
        den += (w0 + w1) + (w2 + w3);
        a0 = fmaf(w0, bf2f(HA0[0]), a0); a0 = fmaf(w1, bf2f(HA1[0]), a0);
        a0 = fmaf(w2, bf2f(HA2[0]), a0); a0 = fmaf(w3, bf2f(HA3[0]), a0);
        a1 = fmaf(w0, bf2f(HA0[1]), a1); a1 = fmaf(w1, bf2f(HA1[1]), a1);
        a1 = fmaf(w2, bf2f(HA2[1]), a1); a1 = fmaf(w3, bf2f(HA3[1]), a1);
        a2 = fmaf(w0, bf2f(HA0[2]), a2); a2 = fmaf(w1, bf2f(HA1[2]), a2);
        a2 = fmaf(w2, bf2f(HA2[2]), a2); a2 = fmaf(w3, bf2f(HA3[2]), a2);
        a3 = fmaf(w0, bf2f(HA0[3]), a3); a3 = fmaf(w1, bf2f(HA1[3]), a3);
        a3 = fmaf(w2, bf2f(HA2[3]), a3); a3 = fmaf(w3, bf2f(HA3[3]), a3);
        // rotate pipeline registers
        sA0 = sB0; sA1 = sB1; sA2 = sB2; sA3 = sB3;
        rA0 = rB0; rA1 = rB1; rA2 = rB2; rA3 = rB3;
        HA0 = HB0; HA1 = HB1; HA2 = HB2; HA3 = HB3;
        sB0 = sC0; sB1 = sC1; sB2 = sC2; sB3 = sC3;
        rB0 = rC0; rB1 = rC1; rB2 = rC2; rB3 = rC3;
    }
#undef LDI
#undef LDR
#undef LDH
    // combine the two half-wave edge subsets (plain sums, no rescale)
    den += __shfl_xor(den, 32, 64);
    a0  += __shfl_xor(a0, 32, 64);
    a1  += __shfl_xor(a1, 32, 64);
    a2  += __shfl_xor(a2, 32, 64);
    a3  += __shfl_xor(a3, 32, 64);
    const float inv = 1.f / den;
    float v0 = fmaf(a0, inv, bias1[c0 + 0]); v0 = (v0 > 0.f) ? v0 : (__expf(v0) - 1.f);
    float v1 = fmaf(a1, inv, bias1[c0 + 1]); v1 = (v1 > 0.f) ? v1 : (__expf(v1) - 1.f);
    float v2 = fmaf(a2, inv, bias1[c0 + 2]); v2 = (v2 > 0.f) ? v2 : (__expf(v2) - 1.f);
    float v3 = fmaf(a3, inv, bias1[c0 + 3]); v3 = (v3 > 0.f) ? v3 : (__expf(v3) - 1.f);
    float p0 = v0 * W2[(c0 + 0) * 2 + 0] + v1 * W2[(c0 + 1) * 2 + 0]
             + v2 * W2[(c0 + 2) * 2 + 0] + v3 * W2[(c0 + 3) * 2 + 0];
    float p1 = v0 * W2[(c0 + 0) * 2 + 1] + v1 * W2[(c0 + 1) * 2 + 1]
             + v2 * W2[(c0 + 2) * 2 + 1] + v3 * W2[(c0 + 3) * 2 + 1];
    #pragma unroll
    for (int off = 1; off < 32; off <<= 1) {
        p0 += __shfl_xor(p0, off, 64);
        p1 += __shfl_xor(p1, off, 64);
    }
    if (lane == 0) {
        nd[n] = make_float4(p0, p1,
                            p0 * as2[0] + p1 * as2[1],
                            p0 * ad2[0] + p1 * ad2[1]);
    }
}

// =====================================================================
// K4: layer-2 aggregation + fused log_softmax. 4 nodes per wave
//     (16 lanes/node), no max-subtraction (bounded logits).
// =====================================================================
__global__ __launch_bounds__(256) void k_agg2(
        const int* __restrict__ row_ptr, const ushort* __restrict__ csr,
        const float4* __restrict__ nd, const float* __restrict__ bias2,
        float* __restrict__ out) {
    const int lane = threadIdx.x & 63;
    const int wid  = threadIdx.x >> 6;
    const int q = lane >> 4, sl = lane & 15;
    const int n = (blockIdx.x * 4 + wid) * 4 + q;   // 16 nodes per block
    if (n >= N_NODES) return;
    const float adst = nd[n].w;
    const int beg = row_ptr[n], end = row_ptr[n + 1];
    float den = 0.f, a0 = 0.f, a1 = 0.f;
    for (int i = beg + sl; i < end; i += 16) {
        int s = csr[i];
        float4 v = nd[s];
        float e = v.z + adst;
        e = (e > 0.f) ? e : NEG * e;
        float p = __expf(e);
        den += p;
        a0 = fmaf(p, v.x, a0);
        a1 = fmaf(p, v.y, a1);
    }
    #pragma unroll
    for (int off = 1; off < 16; off <<= 1) {     // stays within 16-lane group
        den += __shfl_xor(den, off, 64);
        a0  += __shfl_xor(a0, off, 64);
        a1  += __shfl_xor(a1, off, 64);
    }
    if (sl == 0) {
        float o0 = a0 / den + bias2[0];
        float o1 = a1 / den + bias2[1];
        float mx = fmaxf(o0, o1);
        float lse = mx + logf(__expf(o0 - mx) + __expf(o1 - mx));
        out[n * 2 + 0] = o0 - lse;
        out[n * 2 + 1] = o1 - lse;
    }
}

// =====================================================================
extern "C" void kernel_launch(void* const* d_in, const int* in_sizes, int n_in,
                              void* d_out, int out_size, void* d_ws, size_t ws_size,
                              hipStream_t stream) {
    const float* x   = (const float*)d_in[0];
    const void*  ei  = d_in[1];
    const float* W1  = (const float*)d_in[2];
    const float* as1 = (const float*)d_in[3];
    const float* ad1 = (const float*)d_in[4];
    const float* b1  = (const float*)d_in[5];
    const float* W2  = (const float*)d_in[6];
    const float* as2 = (const float*)d_in[7];
    const float* ad2 = (const float*)d_in[8];
    const float* b2  = (const float*)d_in[9];
    float* out = (float*)d_out;

    char* ws = (char*)d_ws;
    size_t off = 0;
    auto alloc = [&](size_t bytes) -> char* {
        char* p = ws + off;
        off += (bytes + 255) & ~size_t(255);
        return p;
    };
    int*    deg     = (int*)alloc(N_NODES * 4);
    int*    part    = (int*)alloc(N_NODES * 4);
    int*    bsum    = (int*)alloc(NBLK_SCAN * 4);
    int*    row_ptr = (int*)alloc((N_NODES + 1) * 4);
    ushort* csr     = (ushort*)alloc(ETOT * 2);
    ull*    epack   = (ull*)alloc((size_t)ETOT * 8);
    ushort* h1b     = (ushort*)alloc((size_t)N_PAD * HD * 2);
    float*  asrc1   = (float*)alloc((size_t)N_NODES * HEADS * 4);
    float*  adst1   = (float*)alloc((size_t)N_NODES * HEADS * 4);
    float4* nd      = (float4*)alloc((size_t)N_NODES * 16);

    hipMemsetAsync(deg, 0, N_NODES * sizeof(int), stream);
    k_fused<<<NB_GEMM + NB_BUILD, 256, 0, stream>>>(ei, x, W1, as1, ad1,
                                                    deg, epack, h1b, asrc1, adst1);
    k_scan1<<<NBLK_SCAN, 1024, 0, stream>>>(deg, part, bsum);
    k_scatter3<<<(ETOT + 255) / 256, 256, 0, stream>>>(epack, part, bsum, row_ptr, csr);
    k_agg1<<<(N_NODES + 3) / 4, 256, 0, stream>>>(row_ptr, csr, asrc1, adst1,
                                                  h1b, b1, W2, as2, ad2, nd);
    k_agg2<<<(N_NODES + 15) / 16, 256, 0, stream>>>(row_ptr, csr, nd, b2, out);
}